// Round 1
// baseline (5986.874 us; speedup 1.0000x reference)
//
#include <hip/hip_runtime.h>

#define N_NODES_C 1000000
#define N_ELEMS_C 4000000

struct Scalars {
    double S_kin;    // sum of r_kin_i^2 + r_kin_j^2 over elements
    double L_sum;    // sum of elem_lengths
    double S_Fext;   // sum over free_d nodes of |F_ext|^2
    double S_force;  // sum over free_d nodes of |F_int+F_ext|^2
    double S_mom;    // sum over free_r nodes of |M_int|^2
    double S_neu;    // sum over pin nodes of |M_int|^2
    unsigned long long n_fd;
    unsigned long long n_fr;
    unsigned long long n_pin;
    int q_max_bits;  // positive float as int bits (atomicMax-safe)
    int L_max_bits;
};

__device__ __forceinline__ double waveSum(double v) {
    for (int off = 32; off > 0; off >>= 1) v += __shfl_down(v, off, 64);
    return v;
}
__device__ __forceinline__ float waveMax(float v) {
    for (int off = 32; off > 0; off >>= 1) v = fmaxf(v, __shfl_down(v, off, 64));
    return v;
}

__global__ __launch_bounds__(256) void elem_kernel(
    const float* __restrict__ phi,
    const float* __restrict__ grad_ux,
    const float* __restrict__ grad_uz,
    const float* __restrict__ grad_phi,
    const float* __restrict__ prop_E,
    const float* __restrict__ prop_A,
    const float* __restrict__ prop_I22,
    const float* __restrict__ elem_len,
    const float* __restrict__ xhat,
    const float* __restrict__ load,
    const int*   __restrict__ conn,
    float* __restrict__ F_int,
    float* __restrict__ M_int,
    float* __restrict__ F_ext,
    Scalars* __restrict__ sc)
{
    int e = blockIdx.x * blockDim.x + threadIdx.x;
    double kin = 0.0, lsum = 0.0;
    float qm = 0.0f, lm = 0.0f;

    if (e < N_ELEMS_C) {
        size_t i = (size_t)conn[2 * e + 0];
        size_t j = (size_t)conn[2 * e + 1];
        float x0 = xhat[3 * (size_t)e + 0];
        float x1 = xhat[3 * (size_t)e + 1];
        float x2 = xhat[3 * (size_t)e + 2];
        float L  = elem_len[e];
        float E  = prop_E[e];
        float EA = E * prop_A[e];
        float EI = E * prop_I22[e];
        float q0 = load[3 * (size_t)e + 0];
        float q1 = load[3 * (size_t)e + 1];
        float q2 = load[3 * (size_t)e + 2];

        // ---- local axes (matches _local_axes exactly) ----
        bool  par = fabsf(x1) > 0.99f;
        float r1 = par ? 0.0f : 1.0f;
        float r2 = par ? 1.0f : 0.0f;
        // z = cross(x, ref), ref = (0, r1, r2)
        float z0 = x1 * r2 - x2 * r1;
        float z1 = -x0 * r2;
        float z2 =  x0 * r1;
        float zn = fmaxf(sqrtf(z0 * z0 + z1 * z1 + z2 * z2), 1e-8f);
        z0 /= zn; z1 /= zn; z2 /= zn;
        // y = cross(z, x)
        float y0 = z1 * x2 - z2 * x1;
        float y1 = z2 * x0 - z0 * x2;
        float y2 = z0 * x1 - z1 * x0;
        float yn = fmaxf(sqrtf(y0 * y0 + y1 * y1 + y2 * y2), 1e-8f);
        y0 /= yn; y1 /= yn; y2 /= yn;

        // ---- gathers ----
        const float* gui = grad_ux  + 3 * i;
        const float* guj = grad_ux  + 3 * j;
        const float* gzi = grad_uz  + 3 * i;
        const float* gzj = grad_uz  + 3 * j;
        const float* gpi = grad_phi + 3 * i;
        const float* gpj = grad_phi + 3 * j;

        float gux_i_ax = gui[0] * x0 + gui[1] * x1 + gui[2] * x2;
        float gux_j_ax = guj[0] * x0 + guj[1] * x1 + guj[2] * x2;
        float guz_i_ax = gzi[0] * x0 + gzi[1] * x1 + gzi[2] * x2;
        float guz_j_ax = gzj[0] * x0 + gzj[1] * x1 + gzj[2] * x2;
        float kap_i    = gpi[0] * x0 + gpi[1] * x1 + gpi[2] * x2;
        float kap_j    = gpj[0] * x0 + gpj[1] * x1 + gpj[2] * x2;

        float eps_i = x0 * gux_i_ax + x2 * guz_i_ax;
        float eps_j = x0 * gux_j_ax + x2 * guz_j_ax;
        float N_avg = 0.5f * EA * (eps_i + eps_j);
        float M_i = EI * kap_i;
        float M_j = EI * kap_j;
        float V = (M_j - M_i) / L;
        float F0 = N_avg * x0 + V * z0;
        float F1 = N_avg * x1 + V * z1;
        float F2 = N_avg * x2 + V * z2;
        float hl = 0.5f * L;
        float fe0 = q0 * hl, fe1 = q1 * hl, fe2 = q2 * hl;

        // ---- scatters (18 fp32 atomics) ----
        atomicAdd(&F_int[3 * i + 0],  F0);
        atomicAdd(&F_int[3 * i + 1],  F1);
        atomicAdd(&F_int[3 * i + 2],  F2);
        atomicAdd(&F_int[3 * j + 0], -F0);
        atomicAdd(&F_int[3 * j + 1], -F1);
        atomicAdd(&F_int[3 * j + 2], -F2);

        atomicAdd(&M_int[3 * i + 0], M_i * y0);
        atomicAdd(&M_int[3 * i + 1], M_i * y1);
        atomicAdd(&M_int[3 * i + 2], M_i * y2);
        atomicAdd(&M_int[3 * j + 0], M_j * y0);
        atomicAdd(&M_int[3 * j + 1], M_j * y1);
        atomicAdd(&M_int[3 * j + 2], M_j * y2);

        atomicAdd(&F_ext[3 * i + 0], fe0);
        atomicAdd(&F_ext[3 * i + 1], fe1);
        atomicAdd(&F_ext[3 * i + 2], fe2);
        atomicAdd(&F_ext[3 * j + 0], fe0);
        atomicAdd(&F_ext[3 * j + 1], fe1);
        atomicAdd(&F_ext[3 * j + 2], fe2);

        // ---- kinematic residual + scalar partials ----
        float du_i = z0 * gux_i_ax + z2 * guz_i_ax;
        float du_j = z0 * gux_j_ax + z2 * guz_j_ax;
        float rki = phi[i] - du_i;
        float rkj = phi[j] - du_j;
        kin  = (double)rki * (double)rki + (double)rkj * (double)rkj;
        lsum = (double)L;
        qm   = fmaxf(fmaxf(fabsf(q0), fabsf(q1)), fabsf(q2));
        lm   = L;
    }

    kin  = waveSum(kin);
    lsum = waveSum(lsum);
    qm   = waveMax(qm);
    lm   = waveMax(lm);
    if ((threadIdx.x & 63) == 0) {
        atomicAdd(&sc->S_kin, kin);
        atomicAdd(&sc->L_sum, lsum);
        atomicMax(&sc->q_max_bits, __float_as_int(qm));
        atomicMax(&sc->L_max_bits, __float_as_int(lm));
    }
}

__global__ __launch_bounds__(256) void node_kernel(
    const float* __restrict__ bc_disp,
    const float* __restrict__ bc_rot,
    const float* __restrict__ F_int,
    const float* __restrict__ M_int,
    const float* __restrict__ F_ext,
    Scalars* __restrict__ sc)
{
    int n = blockIdx.x * blockDim.x + threadIdx.x;
    double sFext = 0.0, sForce = 0.0, sMom = 0.0, sNeu = 0.0;
    bool fd = false, fr = false, pin = false;

    if (n < N_NODES_C) {
        float bd = bc_disp[n];
        float br = bc_rot[n];
        fd  = bd < 0.5f;
        fr  = br < 0.5f;
        pin = (bd > 0.5f) && (br < 0.5f);

        size_t b = 3 * (size_t)n;
        float fe0 = F_ext[b + 0], fe1 = F_ext[b + 1], fe2 = F_ext[b + 2];
        float fi0 = F_int[b + 0], fi1 = F_int[b + 1], fi2 = F_int[b + 2];
        float m0  = M_int[b + 0], m1  = M_int[b + 1], m2  = M_int[b + 2];

        double fesq = (double)fe0 * fe0 + (double)fe1 * fe1 + (double)fe2 * fe2;
        double s0 = (double)(fi0 + fe0);
        double s1 = (double)(fi1 + fe1);
        double s2 = (double)(fi2 + fe2);
        double fsq = s0 * s0 + s1 * s1 + s2 * s2;
        double msq = (double)m0 * m0 + (double)m1 * m1 + (double)m2 * m2;

        if (fd)  { sFext = fesq; sForce = fsq; }
        if (fr)  { sMom = msq; }
        if (pin) { sNeu = msq; }
    }

    unsigned long long cfd  = __popcll(__ballot(fd));
    unsigned long long cfr  = __popcll(__ballot(fr));
    unsigned long long cpin = __popcll(__ballot(pin));

    sFext  = waveSum(sFext);
    sForce = waveSum(sForce);
    sMom   = waveSum(sMom);
    sNeu   = waveSum(sNeu);

    if ((threadIdx.x & 63) == 0) {
        atomicAdd(&sc->S_Fext,  sFext);
        atomicAdd(&sc->S_force, sForce);
        atomicAdd(&sc->S_mom,   sMom);
        atomicAdd(&sc->S_neu,   sNeu);
        atomicAdd(&sc->n_fd,  cfd);
        atomicAdd(&sc->n_fr,  cfr);
        atomicAdd(&sc->n_pin, cpin);
    }
}

__global__ void finalize_kernel(const Scalars* __restrict__ sc, float* __restrict__ out)
{
    double n_fd = (double)(sc->n_fd > 0ull ? sc->n_fd : 1ull);
    double n_fr = (double)(sc->n_fr > 0ull ? sc->n_fr : 1ull);

    double F_char = sqrt(sc->S_Fext / (3.0 * n_fd));
    if (F_char < 1.0) F_char = 1.0;

    double q_max = (double)__int_as_float(sc->q_max_bits);
    if (q_max < 1.0) q_max = 1.0;
    double L_max = (double)__int_as_float(sc->L_max_bits);
    double M_char = q_max * L_max * sc->L_sum / 8.0;
    if (M_char < 1.0) M_char = 1.0;

    double L_force  = sc->S_force / (3.0 * n_fd) / (F_char * F_char);
    double L_moment = sc->S_mom   / (3.0 * n_fr) / (M_char * M_char);
    double L_neu = 0.0;
    if (sc->n_pin > 0ull) {
        L_neu = sc->S_neu / (3.0 * (double)sc->n_pin) / (M_char * M_char);
    }
    double L_kin = 0.5 * sc->S_kin / (double)N_ELEMS_C;

    out[0] = (float)(1.0 * L_force + 1.0 * L_moment + 1.0 * L_neu + 0.1 * L_kin);
}

extern "C" void kernel_launch(void* const* d_in, const int* in_sizes, int n_in,
                              void* d_out, int out_size, void* d_ws, size_t ws_size,
                              hipStream_t stream) {
    const float* phi       = (const float*)d_in[0];
    const float* grad_ux   = (const float*)d_in[1];
    const float* grad_uz   = (const float*)d_in[2];
    const float* grad_phi  = (const float*)d_in[3];
    const float* prop_E    = (const float*)d_in[4];
    const float* prop_A    = (const float*)d_in[5];
    const float* prop_I22  = (const float*)d_in[6];
    const float* elem_len  = (const float*)d_in[7];
    const float* elem_dir  = (const float*)d_in[8];
    const float* elem_load = (const float*)d_in[9];
    const float* bc_disp   = (const float*)d_in[10];
    const float* bc_rot    = (const float*)d_in[11];
    const int*   conn      = (const int*)d_in[12];

    const size_t nodeArr = 3ull * N_NODES_C;  // floats per node array
    float* F_int = (float*)d_ws;
    float* M_int = F_int + nodeArr;
    float* F_ext = M_int + nodeArr;
    Scalars* sc  = (Scalars*)(F_ext + nodeArr);   // offset 36,000,000 B (8-aligned)

    size_t zero_bytes = nodeArr * 3ull * sizeof(float) + sizeof(Scalars);
    hipMemsetAsync(d_ws, 0, zero_bytes, stream);

    elem_kernel<<<N_ELEMS_C / 256, 256, 0, stream>>>(
        phi, grad_ux, grad_uz, grad_phi,
        prop_E, prop_A, prop_I22, elem_len, elem_dir, elem_load, conn,
        F_int, M_int, F_ext, sc);

    node_kernel<<<(N_NODES_C + 255) / 256, 256, 0, stream>>>(
        bc_disp, bc_rot, F_int, M_int, F_ext, sc);

    finalize_kernel<<<1, 1, 0, stream>>>(sc, (float*)d_out);
}

// Round 3
// 4137.159 us; speedup vs baseline: 1.4471x; 1.4471x over previous
//
#include <hip/hip_runtime.h>

#define N_NODES_C 1000000
#define N_ELEMS_C 4000000
#define N_ENDP_C  (2 * N_ELEMS_C)
#define TILE 1024
#define N_TILES ((N_NODES_C + TILE - 1) / TILE)   // 977

struct Scalars {
    double S_kin;
    double L_sum;
    double S_Fext;
    double S_force;
    double S_mom;
    double S_neu;
    unsigned long long n_fd;
    unsigned long long n_fr;
    unsigned long long n_pin;
    int q_max_bits;
    int L_max_bits;
};

__device__ __forceinline__ double waveSumD(double v) {
    for (int off = 32; off > 0; off >>= 1) v += __shfl_down(v, off, 64);
    return v;
}
__device__ __forceinline__ float waveMaxF(float v) {
    for (int off = 32; off > 0; off >>= 1) v = fmaxf(v, __shfl_down(v, off, 64));
    return v;
}
__device__ __forceinline__ int waveSumI(int v) {
    for (int off = 32; off > 0; off >>= 1) v += __shfl_down(v, off, 64);
    return v;
}

// ============================== Tier B: CSR + recompute ==============================

// K1: histogram + element-stream scalars (L_sum, q_max, L_max)
__global__ __launch_bounds__(256) void hist_scalars(
    const int* __restrict__ conn,
    const float* __restrict__ elem_len,
    const float* __restrict__ load,
    int* __restrict__ counts,
    Scalars* __restrict__ sc)
{
    int e = blockIdx.x * blockDim.x + threadIdx.x;
    double lsum = 0.0;
    float qm = 0.0f, lm = 0.0f;
    if (e < N_ELEMS_C) {
        int2 ij = ((const int2*)conn)[e];
        atomicAdd(&counts[ij.x], 1);   // fire-and-forget
        atomicAdd(&counts[ij.y], 1);
        float L = elem_len[e];
        float q0 = load[3 * (size_t)e + 0];
        float q1 = load[3 * (size_t)e + 1];
        float q2 = load[3 * (size_t)e + 2];
        lsum = (double)L;
        lm = L;
        qm = fmaxf(fmaxf(fabsf(q0), fabsf(q1)), fabsf(q2));
    }
    lsum = waveSumD(lsum);
    qm = waveMaxF(qm);
    lm = waveMaxF(lm);
    if ((threadIdx.x & 63) == 0) {
        atomicAdd(&sc->L_sum, lsum);
        atomicMax(&sc->q_max_bits, __float_as_int(qm));
        atomicMax(&sc->L_max_bits, __float_as_int(lm));
    }
}

// K2a: per-tile sums
__global__ __launch_bounds__(256) void tile_sum(
    const int* __restrict__ counts, int* __restrict__ tileSums)
{
    int tile = blockIdx.x;
    int base = tile * TILE;
    int s = 0;
    for (int k = threadIdx.x; k < TILE; k += 256) {
        int idx = base + k;
        s += (idx < N_NODES_C) ? counts[idx] : 0;
    }
    s = waveSumI(s);
    __shared__ int sh[4];
    if ((threadIdx.x & 63) == 0) sh[threadIdx.x >> 6] = s;
    __syncthreads();
    if (threadIdx.x == 0) tileSums[tile] = sh[0] + sh[1] + sh[2] + sh[3];
}

// K2b: exclusive scan of tile sums (single block)
__global__ __launch_bounds__(1024) void scan_tiles(int* __restrict__ tileSums)
{
    __shared__ int sh[1024];
    int t = threadIdx.x;
    int v = (t < N_TILES) ? tileSums[t] : 0;
    sh[t] = v;
    __syncthreads();
    for (int s = 1; s < 1024; s <<= 1) {
        int a = (t >= s) ? sh[t - s] : 0;
        __syncthreads();
        sh[t] += a;
        __syncthreads();
    }
    if (t < N_TILES) tileSums[t] = sh[t] - v;
}

// K2c: within-tile exclusive scan -> offsets
__global__ __launch_bounds__(256) void scan_within(
    const int* __restrict__ counts, const int* __restrict__ tileSums,
    int* __restrict__ offsets)
{
    int tile = blockIdx.x;
    int base = tile * TILE;
    int t = threadIdx.x;
    int i0 = base + t * 4;
    int c0 = (i0 + 0 < N_NODES_C) ? counts[i0 + 0] : 0;
    int c1 = (i0 + 1 < N_NODES_C) ? counts[i0 + 1] : 0;
    int c2 = (i0 + 2 < N_NODES_C) ? counts[i0 + 2] : 0;
    int c3 = (i0 + 3 < N_NODES_C) ? counts[i0 + 3] : 0;
    int tsum = c0 + c1 + c2 + c3;
    __shared__ int sh[256];
    sh[t] = tsum;
    __syncthreads();
    for (int s = 1; s < 256; s <<= 1) {
        int a = (t >= s) ? sh[t - s] : 0;
        __syncthreads();
        sh[t] += a;
        __syncthreads();
    }
    int run = tileSums[tile] + (sh[t] - tsum);
    if (i0 + 0 < N_NODES_C) offsets[i0 + 0] = run; run += c0;
    if (i0 + 1 < N_NODES_C) offsets[i0 + 1] = run; run += c1;
    if (i0 + 2 < N_NODES_C) offsets[i0 + 2] = run; run += c2;
    if (i0 + 3 < N_NODES_C) offsets[i0 + 3] = run;
}

// K3: fill CSR endpoint tokens (counts is consumed as a cursor via atomicSub)
__global__ __launch_bounds__(256) void fill_csr(
    const int* __restrict__ conn,
    const int* __restrict__ offsets,
    int* __restrict__ counts,
    int* __restrict__ eidside)
{
    int e = blockIdx.x * blockDim.x + threadIdx.x;
    if (e >= N_ELEMS_C) return;
    int2 ij = ((const int2*)conn)[e];
    int oi = atomicSub(&counts[ij.x], 1) - 1;
    eidside[offsets[ij.x] + oi] = (e << 1);
    int oj = atomicSub(&counts[ij.y], 1) - 1;
    eidside[offsets[ij.y] + oj] = (e << 1) | 1;
}

// K4: per-node gather + full recompute + masked loss reduction
__global__ __launch_bounds__(256) void node_reduce_csr(
    const float* __restrict__ phi,
    const float* __restrict__ grad_ux,
    const float* __restrict__ grad_uz,
    const float* __restrict__ grad_phi,
    const float* __restrict__ prop_E,
    const float* __restrict__ prop_A,
    const float* __restrict__ prop_I22,
    const float* __restrict__ elem_len,
    const float* __restrict__ xhat,
    const float* __restrict__ load,
    const int*   __restrict__ conn,
    const float* __restrict__ bc_disp,
    const float* __restrict__ bc_rot,
    const int*   __restrict__ offsets,
    const int*   __restrict__ eidside,
    Scalars* __restrict__ sc)
{
    int n = blockIdx.x * blockDim.x + threadIdx.x;
    double sFext = 0.0, sForce = 0.0, sMom = 0.0, sNeu = 0.0, kin = 0.0;
    bool fd = false, fr = false, pin = false;

    if (n < N_NODES_C) {
        float bd = bc_disp[n];
        float br = bc_rot[n];
        fd  = bd < 0.5f;
        fr  = br < 0.5f;
        pin = (bd > 0.5f) && (br < 0.5f);

        float phin = phi[n];
        size_t b3 = 3 * (size_t)n;
        float ux0 = grad_ux[b3 + 0], ux1 = grad_ux[b3 + 1], ux2 = grad_ux[b3 + 2];
        float uz0 = grad_uz[b3 + 0], uz1 = grad_uz[b3 + 1], uz2 = grad_uz[b3 + 2];
        float gp0 = grad_phi[b3 + 0], gp1 = grad_phi[b3 + 1], gp2 = grad_phi[b3 + 2];

        int beg = offsets[n];
        int end = (n == N_NODES_C - 1) ? N_ENDP_C : offsets[n + 1];

        float fi0 = 0.f, fi1 = 0.f, fi2 = 0.f;
        float m0 = 0.f, m1 = 0.f, m2 = 0.f;
        float fe0 = 0.f, fe1 = 0.f, fe2 = 0.f;

        for (int k = beg; k < end; ++k) {
            int es = eidside[k];
            int e  = es >> 1;
            int s  = es & 1;
            int2 c = ((const int2*)conn)[e];
            size_t other = (size_t)(s ? c.x : c.y);

            size_t e3 = 3 * (size_t)e;
            float x0 = xhat[e3 + 0];
            float x1 = xhat[e3 + 1];
            float x2 = xhat[e3 + 2];
            float L  = elem_len[e];
            float E  = prop_E[e];
            float EA = E * prop_A[e];
            float EI = E * prop_I22[e];
            float q0 = load[e3 + 0];
            float q1 = load[e3 + 1];
            float q2 = load[e3 + 2];

            // local axes (matches _local_axes)
            bool  par = fabsf(x1) > 0.99f;
            float r1 = par ? 0.0f : 1.0f;
            float r2 = par ? 1.0f : 0.0f;
            float z0 = x1 * r2 - x2 * r1;
            float z1 = -x0 * r2;
            float z2 =  x0 * r1;
            float zn = fmaxf(sqrtf(z0 * z0 + z1 * z1 + z2 * z2), 1e-8f);
            z0 /= zn; z1 /= zn; z2 /= zn;
            float y0 = z1 * x2 - z2 * x1;
            float y1 = z2 * x0 - z0 * x2;
            float y2 = z0 * x1 - z1 * x0;
            float yn = fmaxf(sqrtf(y0 * y0 + y1 * y1 + y2 * y2), 1e-8f);
            y0 /= yn; y1 /= yn; y2 /= yn;

            // own-node axial gradients
            float own_ux_ax = ux0 * x0 + ux1 * x1 + ux2 * x2;
            float own_uz_ax = uz0 * x0 + uz1 * x1 + uz2 * x2;
            float kap_own   = gp0 * x0 + gp1 * x1 + gp2 * x2;

            // other-node axial gradients (random gathers)
            size_t o3 = 3 * other;
            float oth_ux_ax = grad_ux[o3 + 0] * x0 + grad_ux[o3 + 1] * x1 + grad_ux[o3 + 2] * x2;
            float oth_uz_ax = grad_uz[o3 + 0] * x0 + grad_uz[o3 + 1] * x1 + grad_uz[o3 + 2] * x2;
            float kap_oth   = grad_phi[o3 + 0] * x0 + grad_phi[o3 + 1] * x1 + grad_phi[o3 + 2] * x2;

            float eps_own = x0 * own_ux_ax + x2 * own_uz_ax;
            float eps_oth = x0 * oth_ux_ax + x2 * oth_uz_ax;
            float N_avg = 0.5f * EA * (eps_own + eps_oth);
            float M_own = EI * kap_own;
            float M_oth = EI * kap_oth;
            float Vz = (M_oth - M_own) / L;         // == (M_j - M_i)/L viewed from either side
            float t = s ? -1.0f : 1.0f;

            fi0 += t * N_avg * x0 + Vz * z0;
            fi1 += t * N_avg * x1 + Vz * z1;
            fi2 += t * N_avg * x2 + Vz * z2;
            m0  += M_own * y0;
            m1  += M_own * y1;
            m2  += M_own * y2;
            float hl = 0.5f * L;
            fe0 += q0 * hl;
            fe1 += q1 * hl;
            fe2 += q2 * hl;

            float du = z0 * own_ux_ax + z2 * own_uz_ax;
            float rk = phin - du;
            kin += (double)rk * (double)rk;
        }

        double fesq = (double)fe0 * fe0 + (double)fe1 * fe1 + (double)fe2 * fe2;
        double s0 = (double)(fi0 + fe0);
        double s1 = (double)(fi1 + fe1);
        double s2 = (double)(fi2 + fe2);
        double fsq = s0 * s0 + s1 * s1 + s2 * s2;
        double msq = (double)m0 * m0 + (double)m1 * m1 + (double)m2 * m2;

        if (fd)  { sFext = fesq; sForce = fsq; }
        if (fr)  { sMom = msq; }
        if (pin) { sNeu = msq; }
    }

    unsigned long long cfd  = __popcll(__ballot(fd));
    unsigned long long cfr  = __popcll(__ballot(fr));
    unsigned long long cpin = __popcll(__ballot(pin));

    sFext  = waveSumD(sFext);
    sForce = waveSumD(sForce);
    sMom   = waveSumD(sMom);
    sNeu   = waveSumD(sNeu);
    kin    = waveSumD(kin);

    if ((threadIdx.x & 63) == 0) {
        atomicAdd(&sc->S_Fext,  sFext);
        atomicAdd(&sc->S_force, sForce);
        atomicAdd(&sc->S_mom,   sMom);
        atomicAdd(&sc->S_neu,   sNeu);
        atomicAdd(&sc->S_kin,   kin);
        atomicAdd(&sc->n_fd,  cfd);
        atomicAdd(&sc->n_fr,  cfr);
        atomicAdd(&sc->n_pin, cpin);
    }
}

// ============================== Tier C fallback: round-1 atomics ==============================

__global__ __launch_bounds__(256) void elem_kernel_atomic(
    const float* __restrict__ phi,
    const float* __restrict__ grad_ux,
    const float* __restrict__ grad_uz,
    const float* __restrict__ grad_phi,
    const float* __restrict__ prop_E,
    const float* __restrict__ prop_A,
    const float* __restrict__ prop_I22,
    const float* __restrict__ elem_len,
    const float* __restrict__ xhat,
    const float* __restrict__ load,
    const int*   __restrict__ conn,
    float* __restrict__ F_int,
    float* __restrict__ M_int,
    float* __restrict__ F_ext,
    Scalars* __restrict__ sc)
{
    int e = blockIdx.x * blockDim.x + threadIdx.x;
    double kin = 0.0, lsum = 0.0;
    float qm = 0.0f, lm = 0.0f;

    if (e < N_ELEMS_C) {
        size_t i = (size_t)conn[2 * e + 0];
        size_t j = (size_t)conn[2 * e + 1];
        float x0 = xhat[3 * (size_t)e + 0];
        float x1 = xhat[3 * (size_t)e + 1];
        float x2 = xhat[3 * (size_t)e + 2];
        float L  = elem_len[e];
        float E  = prop_E[e];
        float EA = E * prop_A[e];
        float EI = E * prop_I22[e];
        float q0 = load[3 * (size_t)e + 0];
        float q1 = load[3 * (size_t)e + 1];
        float q2 = load[3 * (size_t)e + 2];

        bool  par = fabsf(x1) > 0.99f;
        float r1 = par ? 0.0f : 1.0f;
        float r2 = par ? 1.0f : 0.0f;
        float z0 = x1 * r2 - x2 * r1;
        float z1 = -x0 * r2;
        float z2 =  x0 * r1;
        float zn = fmaxf(sqrtf(z0 * z0 + z1 * z1 + z2 * z2), 1e-8f);
        z0 /= zn; z1 /= zn; z2 /= zn;
        float y0 = z1 * x2 - z2 * x1;
        float y1 = z2 * x0 - z0 * x2;
        float y2 = z0 * x1 - z1 * x0;
        float yn = fmaxf(sqrtf(y0 * y0 + y1 * y1 + y2 * y2), 1e-8f);
        y0 /= yn; y1 /= yn; y2 /= yn;

        const float* gui = grad_ux  + 3 * i;
        const float* guj = grad_ux  + 3 * j;
        const float* gzi = grad_uz  + 3 * i;
        const float* gzj = grad_uz  + 3 * j;
        const float* gpi = grad_phi + 3 * i;
        const float* gpj = grad_phi + 3 * j;

        float gux_i_ax = gui[0] * x0 + gui[1] * x1 + gui[2] * x2;
        float gux_j_ax = guj[0] * x0 + guj[1] * x1 + guj[2] * x2;
        float guz_i_ax = gzi[0] * x0 + gzi[1] * x1 + gzi[2] * x2;
        float guz_j_ax = gzj[0] * x0 + gzj[1] * x1 + gzj[2] * x2;
        float kap_i    = gpi[0] * x0 + gpi[1] * x1 + gpi[2] * x2;
        float kap_j    = gpj[0] * x0 + gpj[1] * x1 + gpj[2] * x2;

        float eps_i = x0 * gux_i_ax + x2 * guz_i_ax;
        float eps_j = x0 * gux_j_ax + x2 * guz_j_ax;
        float N_avg = 0.5f * EA * (eps_i + eps_j);
        float M_i = EI * kap_i;
        float M_j = EI * kap_j;
        float V = (M_j - M_i) / L;
        float F0 = N_avg * x0 + V * z0;
        float F1 = N_avg * x1 + V * z1;
        float F2 = N_avg * x2 + V * z2;
        float hl = 0.5f * L;
        float fe0 = q0 * hl, fe1 = q1 * hl, fe2 = q2 * hl;

        atomicAdd(&F_int[3 * i + 0],  F0);
        atomicAdd(&F_int[3 * i + 1],  F1);
        atomicAdd(&F_int[3 * i + 2],  F2);
        atomicAdd(&F_int[3 * j + 0], -F0);
        atomicAdd(&F_int[3 * j + 1], -F1);
        atomicAdd(&F_int[3 * j + 2], -F2);
        atomicAdd(&M_int[3 * i + 0], M_i * y0);
        atomicAdd(&M_int[3 * i + 1], M_i * y1);
        atomicAdd(&M_int[3 * i + 2], M_i * y2);
        atomicAdd(&M_int[3 * j + 0], M_j * y0);
        atomicAdd(&M_int[3 * j + 1], M_j * y1);
        atomicAdd(&M_int[3 * j + 2], M_j * y2);
        atomicAdd(&F_ext[3 * i + 0], fe0);
        atomicAdd(&F_ext[3 * i + 1], fe1);
        atomicAdd(&F_ext[3 * i + 2], fe2);
        atomicAdd(&F_ext[3 * j + 0], fe0);
        atomicAdd(&F_ext[3 * j + 1], fe1);
        atomicAdd(&F_ext[3 * j + 2], fe2);

        float du_i = z0 * gux_i_ax + z2 * guz_i_ax;
        float du_j = z0 * gux_j_ax + z2 * guz_j_ax;
        float rki = phi[i] - du_i;
        float rkj = phi[j] - du_j;
        kin  = (double)rki * (double)rki + (double)rkj * (double)rkj;
        lsum = (double)L;
        qm   = fmaxf(fmaxf(fabsf(q0), fabsf(q1)), fabsf(q2));
        lm   = L;
    }

    kin  = waveSumD(kin);
    lsum = waveSumD(lsum);
    qm   = waveMaxF(qm);
    lm   = waveMaxF(lm);
    if ((threadIdx.x & 63) == 0) {
        atomicAdd(&sc->S_kin, kin);
        atomicAdd(&sc->L_sum, lsum);
        atomicMax(&sc->q_max_bits, __float_as_int(qm));
        atomicMax(&sc->L_max_bits, __float_as_int(lm));
    }
}

__global__ __launch_bounds__(256) void node_kernel_atomic(
    const float* __restrict__ bc_disp,
    const float* __restrict__ bc_rot,
    const float* __restrict__ F_int,
    const float* __restrict__ M_int,
    const float* __restrict__ F_ext,
    Scalars* __restrict__ sc)
{
    int n = blockIdx.x * blockDim.x + threadIdx.x;
    double sFext = 0.0, sForce = 0.0, sMom = 0.0, sNeu = 0.0;
    bool fd = false, fr = false, pin = false;

    if (n < N_NODES_C) {
        float bd = bc_disp[n];
        float br = bc_rot[n];
        fd  = bd < 0.5f;
        fr  = br < 0.5f;
        pin = (bd > 0.5f) && (br < 0.5f);

        size_t b = 3 * (size_t)n;
        float fe0 = F_ext[b + 0], fe1 = F_ext[b + 1], fe2 = F_ext[b + 2];
        float fi0 = F_int[b + 0], fi1 = F_int[b + 1], fi2 = F_int[b + 2];
        float m0  = M_int[b + 0], m1  = M_int[b + 1], m2  = M_int[b + 2];

        double fesq = (double)fe0 * fe0 + (double)fe1 * fe1 + (double)fe2 * fe2;
        double s0 = (double)(fi0 + fe0);
        double s1 = (double)(fi1 + fe1);
        double s2 = (double)(fi2 + fe2);
        double fsq = s0 * s0 + s1 * s1 + s2 * s2;
        double msq = (double)m0 * m0 + (double)m1 * m1 + (double)m2 * m2;

        if (fd)  { sFext = fesq; sForce = fsq; }
        if (fr)  { sMom = msq; }
        if (pin) { sNeu = msq; }
    }

    unsigned long long cfd  = __popcll(__ballot(fd));
    unsigned long long cfr  = __popcll(__ballot(fr));
    unsigned long long cpin = __popcll(__ballot(pin));

    sFext  = waveSumD(sFext);
    sForce = waveSumD(sForce);
    sMom   = waveSumD(sMom);
    sNeu   = waveSumD(sNeu);

    if ((threadIdx.x & 63) == 0) {
        atomicAdd(&sc->S_Fext,  sFext);
        atomicAdd(&sc->S_force, sForce);
        atomicAdd(&sc->S_mom,   sMom);
        atomicAdd(&sc->S_neu,   sNeu);
        atomicAdd(&sc->n_fd,  cfd);
        atomicAdd(&sc->n_fr,  cfr);
        atomicAdd(&sc->n_pin, cpin);
    }
}

// ============================== finalize ==============================

__global__ void finalize_kernel(const Scalars* __restrict__ sc, float* __restrict__ out)
{
    double n_fd = (double)(sc->n_fd > 0ull ? sc->n_fd : 1ull);
    double n_fr = (double)(sc->n_fr > 0ull ? sc->n_fr : 1ull);

    double F_char = sqrt(sc->S_Fext / (3.0 * n_fd));
    if (F_char < 1.0) F_char = 1.0;

    double q_max = (double)__int_as_float(sc->q_max_bits);
    if (q_max < 1.0) q_max = 1.0;
    double L_max = (double)__int_as_float(sc->L_max_bits);
    double M_char = q_max * L_max * sc->L_sum / 8.0;
    if (M_char < 1.0) M_char = 1.0;

    double L_force  = sc->S_force / (3.0 * n_fd) / (F_char * F_char);
    double L_moment = sc->S_mom   / (3.0 * n_fr) / (M_char * M_char);
    double L_neu = 0.0;
    if (sc->n_pin > 0ull) {
        L_neu = sc->S_neu / (3.0 * (double)sc->n_pin) / (M_char * M_char);
    }
    double L_kin = 0.5 * sc->S_kin / (double)N_ELEMS_C;

    out[0] = (float)(1.0 * L_force + 1.0 * L_moment + 1.0 * L_neu + 0.1 * L_kin);
}

// ============================== host ==============================

extern "C" void kernel_launch(void* const* d_in, const int* in_sizes, int n_in,
                              void* d_out, int out_size, void* d_ws, size_t ws_size,
                              hipStream_t stream) {
    const float* phi       = (const float*)d_in[0];
    const float* grad_ux   = (const float*)d_in[1];
    const float* grad_uz   = (const float*)d_in[2];
    const float* grad_phi  = (const float*)d_in[3];
    const float* prop_E    = (const float*)d_in[4];
    const float* prop_A    = (const float*)d_in[5];
    const float* prop_I22  = (const float*)d_in[6];
    const float* elem_len  = (const float*)d_in[7];
    const float* elem_dir  = (const float*)d_in[8];
    const float* elem_load = (const float*)d_in[9];
    const float* bc_disp   = (const float*)d_in[10];
    const float* bc_rot    = (const float*)d_in[11];
    const int*   conn      = (const int*)d_in[12];

    // Tier B layout: [counts 4MB][sc 128][offsets 4MB][tileSums 4KB][eidside 32MB]
    const size_t szCounts  = (size_t)N_NODES_C * 4;          // 4,000,000
    const size_t szSc      = 128;
    const size_t szOffsets = (size_t)N_NODES_C * 4;          // 4,000,000
    const size_t szTiles   = 4096;
    const size_t szEid     = (size_t)N_ENDP_C * 4;           // 32,000,000
    const size_t needB = szCounts + szSc + szOffsets + szTiles + szEid;  // ~40.01 MB

    if (ws_size >= needB) {
        char* p = (char*)d_ws;
        int* counts   = (int*)p;      p += szCounts;
        Scalars* sc   = (Scalars*)p;  p += szSc;
        int* offsets  = (int*)p;      p += szOffsets;
        int* tileSums = (int*)p;      p += szTiles;
        int* eidside  = (int*)p;

        hipMemsetAsync(counts, 0, szCounts + szSc, stream);  // counts + sc contiguous

        hist_scalars<<<(N_ELEMS_C + 255) / 256, 256, 0, stream>>>(
            conn, elem_len, elem_load, counts, sc);
        tile_sum<<<N_TILES, 256, 0, stream>>>(counts, tileSums);
        scan_tiles<<<1, 1024, 0, stream>>>(tileSums);
        scan_within<<<N_TILES, 256, 0, stream>>>(counts, tileSums, offsets);
        fill_csr<<<(N_ELEMS_C + 255) / 256, 256, 0, stream>>>(
            conn, offsets, counts, eidside);
        node_reduce_csr<<<(N_NODES_C + 255) / 256, 256, 0, stream>>>(
            phi, grad_ux, grad_uz, grad_phi,
            prop_E, prop_A, prop_I22, elem_len, elem_dir, elem_load, conn,
            bc_disp, bc_rot, offsets, eidside, sc);
        finalize_kernel<<<1, 1, 0, stream>>>(sc, (float*)d_out);
    } else {
        // Tier C fallback (round-1 structure, 36 MB + 128 B)
        const size_t nodeArr = 3ull * N_NODES_C;
        float* F_int = (float*)d_ws;
        float* M_int = F_int + nodeArr;
        float* F_ext = M_int + nodeArr;
        Scalars* sc  = (Scalars*)(F_ext + nodeArr);

        hipMemsetAsync(d_ws, 0, nodeArr * 3ull * sizeof(float) + sizeof(Scalars), stream);

        elem_kernel_atomic<<<N_ELEMS_C / 256, 256, 0, stream>>>(
            phi, grad_ux, grad_uz, grad_phi,
            prop_E, prop_A, prop_I22, elem_len, elem_dir, elem_load, conn,
            F_int, M_int, F_ext, sc);
        node_kernel_atomic<<<(N_NODES_C + 255) / 256, 256, 0, stream>>>(
            bc_disp, bc_rot, F_int, M_int, F_ext, sc);
        finalize_kernel<<<1, 1, 0, stream>>>(sc, (float*)d_out);
    }
}

// Round 4
// 3852.810 us; speedup vs baseline: 1.5539x; 1.0738x over previous
//
#include <hip/hip_runtime.h>

#define N_NODES_C 1000000
#define N_ELEMS_C 4000000
#define N_ENDP_C  (2 * N_ELEMS_C)
#define TILE 1024
#define N_TILES ((N_NODES_C + TILE - 1) / TILE)   // 977

struct Scalars {
    double S_kin;
    double L_sum;
    double S_Fext;
    double S_force;
    double S_mom;
    double S_neu;
    unsigned long long n_fd;
    unsigned long long n_fr;
    unsigned long long n_pin;
    int q_max_bits;
    int L_max_bits;
};

__device__ __forceinline__ double waveSumD(double v) {
    for (int off = 32; off > 0; off >>= 1) v += __shfl_down(v, off, 64);
    return v;
}
__device__ __forceinline__ float waveMaxF(float v) {
    for (int off = 32; off > 0; off >>= 1) v = fmaxf(v, __shfl_down(v, off, 64));
    return v;
}
__device__ __forceinline__ int waveSumI(int v) {
    for (int off = 32; off > 0; off >>= 1) v += __shfl_down(v, off, 64);
    return v;
}

// ============ build kernels ============

// A1/B1: histogram with rank capture + element-stream scalars (8M atomics)
__global__ __launch_bounds__(256) void rank_build(
    const int* __restrict__ conn,
    const float* __restrict__ elem_len,
    const float* __restrict__ load,
    int* __restrict__ counts,
    int2* __restrict__ rank2,
    Scalars* __restrict__ sc)
{
    int e = blockIdx.x * blockDim.x + threadIdx.x;
    double lsum = 0.0;
    float qm = 0.0f, lm = 0.0f;
    if (e < N_ELEMS_C) {
        int2 ij = ((const int2*)conn)[e];
        int ri = atomicAdd(&counts[ij.x], 1);
        int rj = atomicAdd(&counts[ij.y], 1);
        rank2[e] = make_int2(ri, rj);
        float L = elem_len[e];
        float q0 = load[3 * (size_t)e + 0];
        float q1 = load[3 * (size_t)e + 1];
        float q2 = load[3 * (size_t)e + 2];
        lsum = (double)L;
        lm = L;
        qm = fmaxf(fmaxf(fabsf(q0), fabsf(q1)), fabsf(q2));
    }
    lsum = waveSumD(lsum);
    qm = waveMaxF(qm);
    lm = waveMaxF(lm);
    if ((threadIdx.x & 63) == 0) {
        atomicAdd(&sc->L_sum, lsum);
        atomicMax(&sc->q_max_bits, __float_as_int(qm));
        atomicMax(&sc->L_max_bits, __float_as_int(lm));
    }
}

// A2/B: histogram only + element-stream scalars
__global__ __launch_bounds__(256) void hist_scalars(
    const int* __restrict__ conn,
    const float* __restrict__ elem_len,
    const float* __restrict__ load,
    int* __restrict__ counts,
    Scalars* __restrict__ sc)
{
    int e = blockIdx.x * blockDim.x + threadIdx.x;
    double lsum = 0.0;
    float qm = 0.0f, lm = 0.0f;
    if (e < N_ELEMS_C) {
        int2 ij = ((const int2*)conn)[e];
        atomicAdd(&counts[ij.x], 1);
        atomicAdd(&counts[ij.y], 1);
        float L = elem_len[e];
        float q0 = load[3 * (size_t)e + 0];
        float q1 = load[3 * (size_t)e + 1];
        float q2 = load[3 * (size_t)e + 2];
        lsum = (double)L;
        lm = L;
        qm = fmaxf(fmaxf(fabsf(q0), fabsf(q1)), fabsf(q2));
    }
    lsum = waveSumD(lsum);
    qm = waveMaxF(qm);
    lm = waveMaxF(lm);
    if ((threadIdx.x & 63) == 0) {
        atomicAdd(&sc->L_sum, lsum);
        atomicMax(&sc->q_max_bits, __float_as_int(qm));
        atomicMax(&sc->L_max_bits, __float_as_int(lm));
    }
}

// ============ scan kernels (verified R3) ============

__global__ __launch_bounds__(256) void tile_sum(
    const int* __restrict__ counts, int* __restrict__ tileSums)
{
    int tile = blockIdx.x;
    int base = tile * TILE;
    int s = 0;
    for (int k = threadIdx.x; k < TILE; k += 256) {
        int idx = base + k;
        s += (idx < N_NODES_C) ? counts[idx] : 0;
    }
    s = waveSumI(s);
    __shared__ int sh[4];
    if ((threadIdx.x & 63) == 0) sh[threadIdx.x >> 6] = s;
    __syncthreads();
    if (threadIdx.x == 0) tileSums[tile] = sh[0] + sh[1] + sh[2] + sh[3];
}

__global__ __launch_bounds__(1024) void scan_tiles(int* __restrict__ tileSums)
{
    __shared__ int sh[1024];
    int t = threadIdx.x;
    int v = (t < N_TILES) ? tileSums[t] : 0;
    sh[t] = v;
    __syncthreads();
    for (int s = 1; s < 1024; s <<= 1) {
        int a = (t >= s) ? sh[t - s] : 0;
        __syncthreads();
        sh[t] += a;
        __syncthreads();
    }
    if (t < N_TILES) tileSums[t] = sh[t] - v;
}

__global__ __launch_bounds__(256) void scan_within(
    const int* __restrict__ counts, const int* __restrict__ tileSums,
    int* __restrict__ offsets)
{
    int tile = blockIdx.x;
    int base = tile * TILE;
    int t = threadIdx.x;
    int i0 = base + t * 4;
    int c0 = (i0 + 0 < N_NODES_C) ? counts[i0 + 0] : 0;
    int c1 = (i0 + 1 < N_NODES_C) ? counts[i0 + 1] : 0;
    int c2 = (i0 + 2 < N_NODES_C) ? counts[i0 + 2] : 0;
    int c3 = (i0 + 3 < N_NODES_C) ? counts[i0 + 3] : 0;
    int tsum = c0 + c1 + c2 + c3;
    __shared__ int sh[256];
    sh[t] = tsum;
    __syncthreads();
    for (int s = 1; s < 256; s <<= 1) {
        int a = (t >= s) ? sh[t - s] : 0;
        __syncthreads();
        sh[t] += a;
        __syncthreads();
    }
    int run = tileSums[tile] + (sh[t] - tsum);
    if (i0 + 0 < N_NODES_C) offsets[i0 + 0] = run; run += c0;
    if (i0 + 1 < N_NODES_C) offsets[i0 + 1] = run; run += c1;
    if (i0 + 2 < N_NODES_C) offsets[i0 + 2] = run; run += c2;
    if (i0 + 3 < N_NODES_C) offsets[i0 + 3] = run;
}

// ============ fill kernels ============

// B1: tokens only, via saved ranks (no atomics)
__global__ __launch_bounds__(256) void fill_rank(
    const int* __restrict__ conn,
    const int2* __restrict__ rank2,
    const int* __restrict__ offsets,
    int* __restrict__ eidside)
{
    int e = blockIdx.x * blockDim.x + threadIdx.x;
    if (e >= N_ELEMS_C) return;
    int2 ij = ((const int2*)conn)[e];
    int2 rr = rank2[e];
    eidside[offsets[ij.x] + rr.x] = (e << 1);
    eidside[offsets[ij.y] + rr.y] = (e << 1) | 1;
}

// B: tokens via cursor (R3 verified)
__global__ __launch_bounds__(256) void fill_csr(
    const int* __restrict__ conn,
    const int* __restrict__ offsets,
    int* __restrict__ counts,
    int* __restrict__ eidside)
{
    int e = blockIdx.x * blockDim.x + threadIdx.x;
    if (e >= N_ELEMS_C) return;
    int2 ij = ((const int2*)conn)[e];
    int oi = atomicSub(&counts[ij.x], 1) - 1;
    eidside[offsets[ij.x] + oi] = (e << 1);
    int oj = atomicSub(&counts[ij.y], 1) - 1;
    eidside[offsets[ij.y] + oj] = (e << 1) | 1;
}

// A1/A2: element physics -> packed 48B record + CSR tokens.
// rec[3e+0]={x0,x1,x2,N_avg} rec[3e+1]={V,M_i,M_j,0} rec[3e+2]={fe0,fe1,fe2,0}
// If rank2 != nullptr use saved ranks, else atomicSub cursor on counts.
__global__ __launch_bounds__(256) void pack_fill(
    const float* __restrict__ grad_ux,
    const float* __restrict__ grad_uz,
    const float* __restrict__ grad_phi,
    const float* __restrict__ prop_E,
    const float* __restrict__ prop_A,
    const float* __restrict__ prop_I22,
    const float* __restrict__ elem_len,
    const float* __restrict__ xhat,
    const float* __restrict__ load,
    const int*   __restrict__ conn,
    const int*   __restrict__ offsets,
    int* __restrict__ counts,
    const int2* __restrict__ rank2,
    int* __restrict__ eidside,
    float4* __restrict__ rec)
{
    int e = blockIdx.x * blockDim.x + threadIdx.x;
    if (e >= N_ELEMS_C) return;
    int2 ij = ((const int2*)conn)[e];

    int oi, oj;
    if (rank2) {
        int2 rr = rank2[e];
        oi = rr.x; oj = rr.y;
    } else {
        oi = atomicSub(&counts[ij.x], 1) - 1;
        oj = atomicSub(&counts[ij.y], 1) - 1;
    }
    eidside[offsets[ij.x] + oi] = (e << 1);
    eidside[offsets[ij.y] + oj] = (e << 1) | 1;

    size_t e3 = 3 * (size_t)e;
    float x0 = xhat[e3 + 0];
    float x1 = xhat[e3 + 1];
    float x2 = xhat[e3 + 2];
    float L  = elem_len[e];
    float E  = prop_E[e];
    float EA = E * prop_A[e];
    float EI = E * prop_I22[e];
    float q0 = load[e3 + 0];
    float q1 = load[e3 + 1];
    float q2 = load[e3 + 2];

    size_t i3 = 3 * (size_t)ij.x;
    size_t j3 = 3 * (size_t)ij.y;
    float gux_i_ax = grad_ux[i3 + 0] * x0 + grad_ux[i3 + 1] * x1 + grad_ux[i3 + 2] * x2;
    float gux_j_ax = grad_ux[j3 + 0] * x0 + grad_ux[j3 + 1] * x1 + grad_ux[j3 + 2] * x2;
    float guz_i_ax = grad_uz[i3 + 0] * x0 + grad_uz[i3 + 1] * x1 + grad_uz[i3 + 2] * x2;
    float guz_j_ax = grad_uz[j3 + 0] * x0 + grad_uz[j3 + 1] * x1 + grad_uz[j3 + 2] * x2;
    float kap_i    = grad_phi[i3 + 0] * x0 + grad_phi[i3 + 1] * x1 + grad_phi[i3 + 2] * x2;
    float kap_j    = grad_phi[j3 + 0] * x0 + grad_phi[j3 + 1] * x1 + grad_phi[j3 + 2] * x2;

    float eps_i = x0 * gux_i_ax + x2 * guz_i_ax;
    float eps_j = x0 * gux_j_ax + x2 * guz_j_ax;
    float N_avg = 0.5f * EA * (eps_i + eps_j);
    float M_i = EI * kap_i;
    float M_j = EI * kap_j;
    float V = (M_j - M_i) / L;
    float hl = 0.5f * L;

    rec[e3 + 0] = make_float4(x0, x1, x2, N_avg);
    rec[e3 + 1] = make_float4(V, M_i, M_j, 0.0f);
    rec[e3 + 2] = make_float4(q0 * hl, q1 * hl, q2 * hl, 0.0f);
}

// ============ node passes ============

// A: gather packed records (1 token + 1 rec line per endpoint)
__global__ __launch_bounds__(256) void node_pass_A(
    const float* __restrict__ phi,
    const float* __restrict__ grad_ux,
    const float* __restrict__ grad_uz,
    const float* __restrict__ bc_disp,
    const float* __restrict__ bc_rot,
    const int*   __restrict__ offsets,
    const int*   __restrict__ eidside,
    const float4* __restrict__ rec,
    Scalars* __restrict__ sc)
{
    int n = blockIdx.x * blockDim.x + threadIdx.x;
    double sFext = 0.0, sForce = 0.0, sMom = 0.0, sNeu = 0.0, kin = 0.0;
    bool fd = false, fr = false, pin = false;

    if (n < N_NODES_C) {
        float bd = bc_disp[n];
        float br = bc_rot[n];
        fd  = bd < 0.5f;
        fr  = br < 0.5f;
        pin = (bd > 0.5f) && (br < 0.5f);

        float phin = phi[n];
        size_t b3 = 3 * (size_t)n;
        float ux0 = grad_ux[b3 + 0], ux1 = grad_ux[b3 + 1], ux2 = grad_ux[b3 + 2];
        float uz0 = grad_uz[b3 + 0], uz1 = grad_uz[b3 + 1], uz2 = grad_uz[b3 + 2];

        int beg = offsets[n];
        int end = (n == N_NODES_C - 1) ? N_ENDP_C : offsets[n + 1];

        float fi0 = 0.f, fi1 = 0.f, fi2 = 0.f;
        float m0 = 0.f, m1 = 0.f, m2 = 0.f;
        float fe0 = 0.f, fe1 = 0.f, fe2 = 0.f;

        for (int k = beg; k < end; ++k) {
            int es = eidside[k];
            size_t e3 = 3 * (size_t)(es >> 1);
            int s = es & 1;
            float4 r0 = rec[e3 + 0];
            float4 r1 = rec[e3 + 1];
            float4 r2 = rec[e3 + 2];
            float x0 = r0.x, x1 = r0.y, x2 = r0.z, N_avg = r0.w;
            float V = r1.x;
            float M_own = s ? r1.z : r1.y;

            // local axes (matches _local_axes exactly)
            bool  par = fabsf(x1) > 0.99f;
            float rr1 = par ? 0.0f : 1.0f;
            float rr2 = par ? 1.0f : 0.0f;
            float z0 = x1 * rr2 - x2 * rr1;
            float z1 = -x0 * rr2;
            float z2 =  x0 * rr1;
            float zn = fmaxf(sqrtf(z0 * z0 + z1 * z1 + z2 * z2), 1e-8f);
            z0 /= zn; z1 /= zn; z2 /= zn;
            float y0 = z1 * x2 - z2 * x1;
            float y1 = z2 * x0 - z0 * x2;
            float y2 = z0 * x1 - z1 * x0;
            float yn = fmaxf(sqrtf(y0 * y0 + y1 * y1 + y2 * y2), 1e-8f);
            y0 /= yn; y1 /= yn; y2 /= yn;

            float tt = s ? -1.0f : 1.0f;
            fi0 += tt * (N_avg * x0 + V * z0);
            fi1 += tt * (N_avg * x1 + V * z1);
            fi2 += tt * (N_avg * x2 + V * z2);
            m0 += M_own * y0;
            m1 += M_own * y1;
            m2 += M_own * y2;
            fe0 += r2.x; fe1 += r2.y; fe2 += r2.z;

            float oux = ux0 * x0 + ux1 * x1 + ux2 * x2;
            float ouz = uz0 * x0 + uz1 * x1 + uz2 * x2;
            float du = z0 * oux + z2 * ouz;
            float rk = phin - du;
            kin += (double)rk * (double)rk;
        }

        double fesq = (double)fe0 * fe0 + (double)fe1 * fe1 + (double)fe2 * fe2;
        double s0 = (double)(fi0 + fe0);
        double s1 = (double)(fi1 + fe1);
        double s2 = (double)(fi2 + fe2);
        double fsq = s0 * s0 + s1 * s1 + s2 * s2;
        double msq = (double)m0 * m0 + (double)m1 * m1 + (double)m2 * m2;

        if (fd)  { sFext = fesq; sForce = fsq; }
        if (fr)  { sMom = msq; }
        if (pin) { sNeu = msq; }
    }

    unsigned long long cfd  = __popcll(__ballot(fd));
    unsigned long long cfr  = __popcll(__ballot(fr));
    unsigned long long cpin = __popcll(__ballot(pin));

    sFext  = waveSumD(sFext);
    sForce = waveSumD(sForce);
    sMom   = waveSumD(sMom);
    sNeu   = waveSumD(sNeu);
    kin    = waveSumD(kin);

    if ((threadIdx.x & 63) == 0) {
        atomicAdd(&sc->S_Fext,  sFext);
        atomicAdd(&sc->S_force, sForce);
        atomicAdd(&sc->S_mom,   sMom);
        atomicAdd(&sc->S_neu,   sNeu);
        atomicAdd(&sc->S_kin,   kin);
        atomicAdd(&sc->n_fd,  cfd);
        atomicAdd(&sc->n_fr,  cfr);
        atomicAdd(&sc->n_pin, cpin);
    }
}

// B/B1: full recompute (R3 verified)
__global__ __launch_bounds__(256) void node_reduce_csr(
    const float* __restrict__ phi,
    const float* __restrict__ grad_ux,
    const float* __restrict__ grad_uz,
    const float* __restrict__ grad_phi,
    const float* __restrict__ prop_E,
    const float* __restrict__ prop_A,
    const float* __restrict__ prop_I22,
    const float* __restrict__ elem_len,
    const float* __restrict__ xhat,
    const float* __restrict__ load,
    const int*   __restrict__ conn,
    const float* __restrict__ bc_disp,
    const float* __restrict__ bc_rot,
    const int*   __restrict__ offsets,
    const int*   __restrict__ eidside,
    Scalars* __restrict__ sc)
{
    int n = blockIdx.x * blockDim.x + threadIdx.x;
    double sFext = 0.0, sForce = 0.0, sMom = 0.0, sNeu = 0.0, kin = 0.0;
    bool fd = false, fr = false, pin = false;

    if (n < N_NODES_C) {
        float bd = bc_disp[n];
        float br = bc_rot[n];
        fd  = bd < 0.5f;
        fr  = br < 0.5f;
        pin = (bd > 0.5f) && (br < 0.5f);

        float phin = phi[n];
        size_t b3 = 3 * (size_t)n;
        float ux0 = grad_ux[b3 + 0], ux1 = grad_ux[b3 + 1], ux2 = grad_ux[b3 + 2];
        float uz0 = grad_uz[b3 + 0], uz1 = grad_uz[b3 + 1], uz2 = grad_uz[b3 + 2];
        float gp0 = grad_phi[b3 + 0], gp1 = grad_phi[b3 + 1], gp2 = grad_phi[b3 + 2];

        int beg = offsets[n];
        int end = (n == N_NODES_C - 1) ? N_ENDP_C : offsets[n + 1];

        float fi0 = 0.f, fi1 = 0.f, fi2 = 0.f;
        float m0 = 0.f, m1 = 0.f, m2 = 0.f;
        float fe0 = 0.f, fe1 = 0.f, fe2 = 0.f;

        for (int k = beg; k < end; ++k) {
            int es = eidside[k];
            int e  = es >> 1;
            int s  = es & 1;
            int2 c = ((const int2*)conn)[e];
            size_t other = (size_t)(s ? c.x : c.y);

            size_t e3 = 3 * (size_t)e;
            float x0 = xhat[e3 + 0];
            float x1 = xhat[e3 + 1];
            float x2 = xhat[e3 + 2];
            float L  = elem_len[e];
            float E  = prop_E[e];
            float EA = E * prop_A[e];
            float EI = E * prop_I22[e];
            float q0 = load[e3 + 0];
            float q1 = load[e3 + 1];
            float q2 = load[e3 + 2];

            bool  par = fabsf(x1) > 0.99f;
            float r1 = par ? 0.0f : 1.0f;
            float r2 = par ? 1.0f : 0.0f;
            float z0 = x1 * r2 - x2 * r1;
            float z1 = -x0 * r2;
            float z2 =  x0 * r1;
            float zn = fmaxf(sqrtf(z0 * z0 + z1 * z1 + z2 * z2), 1e-8f);
            z0 /= zn; z1 /= zn; z2 /= zn;
            float y0 = z1 * x2 - z2 * x1;
            float y1 = z2 * x0 - z0 * x2;
            float y2 = z0 * x1 - z1 * x0;
            float yn = fmaxf(sqrtf(y0 * y0 + y1 * y1 + y2 * y2), 1e-8f);
            y0 /= yn; y1 /= yn; y2 /= yn;

            float own_ux_ax = ux0 * x0 + ux1 * x1 + ux2 * x2;
            float own_uz_ax = uz0 * x0 + uz1 * x1 + uz2 * x2;
            float kap_own   = gp0 * x0 + gp1 * x1 + gp2 * x2;

            size_t o3 = 3 * other;
            float oth_ux_ax = grad_ux[o3 + 0] * x0 + grad_ux[o3 + 1] * x1 + grad_ux[o3 + 2] * x2;
            float oth_uz_ax = grad_uz[o3 + 0] * x0 + grad_uz[o3 + 1] * x1 + grad_uz[o3 + 2] * x2;
            float kap_oth   = grad_phi[o3 + 0] * x0 + grad_phi[o3 + 1] * x1 + grad_phi[o3 + 2] * x2;

            float eps_own = x0 * own_ux_ax + x2 * own_uz_ax;
            float eps_oth = x0 * oth_ux_ax + x2 * oth_uz_ax;
            float N_avg = 0.5f * EA * (eps_own + eps_oth);
            float M_own = EI * kap_own;
            float M_oth = EI * kap_oth;
            float Vz = (M_oth - M_own) / L;
            float t = s ? -1.0f : 1.0f;

            fi0 += t * N_avg * x0 + Vz * z0;
            fi1 += t * N_avg * x1 + Vz * z1;
            fi2 += t * N_avg * x2 + Vz * z2;
            m0  += M_own * y0;
            m1  += M_own * y1;
            m2  += M_own * y2;
            float hl = 0.5f * L;
            fe0 += q0 * hl;
            fe1 += q1 * hl;
            fe2 += q2 * hl;

            float du = z0 * own_ux_ax + z2 * own_uz_ax;
            float rk = phin - du;
            kin += (double)rk * (double)rk;
        }

        double fesq = (double)fe0 * fe0 + (double)fe1 * fe1 + (double)fe2 * fe2;
        double s0 = (double)(fi0 + fe0);
        double s1 = (double)(fi1 + fe1);
        double s2 = (double)(fi2 + fe2);
        double fsq = s0 * s0 + s1 * s1 + s2 * s2;
        double msq = (double)m0 * m0 + (double)m1 * m1 + (double)m2 * m2;

        if (fd)  { sFext = fesq; sForce = fsq; }
        if (fr)  { sMom = msq; }
        if (pin) { sNeu = msq; }
    }

    unsigned long long cfd  = __popcll(__ballot(fd));
    unsigned long long cfr  = __popcll(__ballot(fr));
    unsigned long long cpin = __popcll(__ballot(pin));

    sFext  = waveSumD(sFext);
    sForce = waveSumD(sForce);
    sMom   = waveSumD(sMom);
    sNeu   = waveSumD(sNeu);
    kin    = waveSumD(kin);

    if ((threadIdx.x & 63) == 0) {
        atomicAdd(&sc->S_Fext,  sFext);
        atomicAdd(&sc->S_force, sForce);
        atomicAdd(&sc->S_mom,   sMom);
        atomicAdd(&sc->S_neu,   sNeu);
        atomicAdd(&sc->S_kin,   kin);
        atomicAdd(&sc->n_fd,  cfd);
        atomicAdd(&sc->n_fr,  cfr);
        atomicAdd(&sc->n_pin, cpin);
    }
}

// ============ Tier C fallback (R1 verified) ============

__global__ __launch_bounds__(256) void elem_kernel_atomic(
    const float* __restrict__ phi,
    const float* __restrict__ grad_ux,
    const float* __restrict__ grad_uz,
    const float* __restrict__ grad_phi,
    const float* __restrict__ prop_E,
    const float* __restrict__ prop_A,
    const float* __restrict__ prop_I22,
    const float* __restrict__ elem_len,
    const float* __restrict__ xhat,
    const float* __restrict__ load,
    const int*   __restrict__ conn,
    float* __restrict__ F_int,
    float* __restrict__ M_int,
    float* __restrict__ F_ext,
    Scalars* __restrict__ sc)
{
    int e = blockIdx.x * blockDim.x + threadIdx.x;
    double kin = 0.0, lsum = 0.0;
    float qm = 0.0f, lm = 0.0f;

    if (e < N_ELEMS_C) {
        size_t i = (size_t)conn[2 * e + 0];
        size_t j = (size_t)conn[2 * e + 1];
        float x0 = xhat[3 * (size_t)e + 0];
        float x1 = xhat[3 * (size_t)e + 1];
        float x2 = xhat[3 * (size_t)e + 2];
        float L  = elem_len[e];
        float E  = prop_E[e];
        float EA = E * prop_A[e];
        float EI = E * prop_I22[e];
        float q0 = load[3 * (size_t)e + 0];
        float q1 = load[3 * (size_t)e + 1];
        float q2 = load[3 * (size_t)e + 2];

        bool  par = fabsf(x1) > 0.99f;
        float r1 = par ? 0.0f : 1.0f;
        float r2 = par ? 1.0f : 0.0f;
        float z0 = x1 * r2 - x2 * r1;
        float z1 = -x0 * r2;
        float z2 =  x0 * r1;
        float zn = fmaxf(sqrtf(z0 * z0 + z1 * z1 + z2 * z2), 1e-8f);
        z0 /= zn; z1 /= zn; z2 /= zn;
        float y0 = z1 * x2 - z2 * x1;
        float y1 = z2 * x0 - z0 * x2;
        float y2 = z0 * x1 - z1 * x0;
        float yn = fmaxf(sqrtf(y0 * y0 + y1 * y1 + y2 * y2), 1e-8f);
        y0 /= yn; y1 /= yn; y2 /= yn;

        const float* gui = grad_ux  + 3 * i;
        const float* guj = grad_ux  + 3 * j;
        const float* gzi = grad_uz  + 3 * i;
        const float* gzj = grad_uz  + 3 * j;
        const float* gpi = grad_phi + 3 * i;
        const float* gpj = grad_phi + 3 * j;

        float gux_i_ax = gui[0] * x0 + gui[1] * x1 + gui[2] * x2;
        float gux_j_ax = guj[0] * x0 + guj[1] * x1 + guj[2] * x2;
        float guz_i_ax = gzi[0] * x0 + gzi[1] * x1 + gzi[2] * x2;
        float guz_j_ax = gzj[0] * x0 + gzj[1] * x1 + gzj[2] * x2;
        float kap_i    = gpi[0] * x0 + gpi[1] * x1 + gpi[2] * x2;
        float kap_j    = gpj[0] * x0 + gpj[1] * x1 + gpj[2] * x2;

        float eps_i = x0 * gux_i_ax + x2 * guz_i_ax;
        float eps_j = x0 * gux_j_ax + x2 * guz_j_ax;
        float N_avg = 0.5f * EA * (eps_i + eps_j);
        float M_i = EI * kap_i;
        float M_j = EI * kap_j;
        float V = (M_j - M_i) / L;
        float F0 = N_avg * x0 + V * z0;
        float F1 = N_avg * x1 + V * z1;
        float F2 = N_avg * x2 + V * z2;
        float hl = 0.5f * L;
        float fe0 = q0 * hl, fe1 = q1 * hl, fe2 = q2 * hl;

        atomicAdd(&F_int[3 * i + 0],  F0);
        atomicAdd(&F_int[3 * i + 1],  F1);
        atomicAdd(&F_int[3 * i + 2],  F2);
        atomicAdd(&F_int[3 * j + 0], -F0);
        atomicAdd(&F_int[3 * j + 1], -F1);
        atomicAdd(&F_int[3 * j + 2], -F2);
        atomicAdd(&M_int[3 * i + 0], M_i * y0);
        atomicAdd(&M_int[3 * i + 1], M_i * y1);
        atomicAdd(&M_int[3 * i + 2], M_i * y2);
        atomicAdd(&M_int[3 * j + 0], M_j * y0);
        atomicAdd(&M_int[3 * j + 1], M_j * y1);
        atomicAdd(&M_int[3 * j + 2], M_j * y2);
        atomicAdd(&F_ext[3 * i + 0], fe0);
        atomicAdd(&F_ext[3 * i + 1], fe1);
        atomicAdd(&F_ext[3 * i + 2], fe2);
        atomicAdd(&F_ext[3 * j + 0], fe0);
        atomicAdd(&F_ext[3 * j + 1], fe1);
        atomicAdd(&F_ext[3 * j + 2], fe2);

        float du_i = z0 * gux_i_ax + z2 * guz_i_ax;
        float du_j = z0 * gux_j_ax + z2 * guz_j_ax;
        float rki = phi[i] - du_i;
        float rkj = phi[j] - du_j;
        kin  = (double)rki * (double)rki + (double)rkj * (double)rkj;
        lsum = (double)L;
        qm   = fmaxf(fmaxf(fabsf(q0), fabsf(q1)), fabsf(q2));
        lm   = L;
    }

    kin  = waveSumD(kin);
    lsum = waveSumD(lsum);
    qm   = waveMaxF(qm);
    lm   = waveMaxF(lm);
    if ((threadIdx.x & 63) == 0) {
        atomicAdd(&sc->S_kin, kin);
        atomicAdd(&sc->L_sum, lsum);
        atomicMax(&sc->q_max_bits, __float_as_int(qm));
        atomicMax(&sc->L_max_bits, __float_as_int(lm));
    }
}

__global__ __launch_bounds__(256) void node_kernel_atomic(
    const float* __restrict__ bc_disp,
    const float* __restrict__ bc_rot,
    const float* __restrict__ F_int,
    const float* __restrict__ M_int,
    const float* __restrict__ F_ext,
    Scalars* __restrict__ sc)
{
    int n = blockIdx.x * blockDim.x + threadIdx.x;
    double sFext = 0.0, sForce = 0.0, sMom = 0.0, sNeu = 0.0;
    bool fd = false, fr = false, pin = false;

    if (n < N_NODES_C) {
        float bd = bc_disp[n];
        float br = bc_rot[n];
        fd  = bd < 0.5f;
        fr  = br < 0.5f;
        pin = (bd > 0.5f) && (br < 0.5f);

        size_t b = 3 * (size_t)n;
        float fe0 = F_ext[b + 0], fe1 = F_ext[b + 1], fe2 = F_ext[b + 2];
        float fi0 = F_int[b + 0], fi1 = F_int[b + 1], fi2 = F_int[b + 2];
        float m0  = M_int[b + 0], m1  = M_int[b + 1], m2  = M_int[b + 2];

        double fesq = (double)fe0 * fe0 + (double)fe1 * fe1 + (double)fe2 * fe2;
        double s0 = (double)(fi0 + fe0);
        double s1 = (double)(fi1 + fe1);
        double s2 = (double)(fi2 + fe2);
        double fsq = s0 * s0 + s1 * s1 + s2 * s2;
        double msq = (double)m0 * m0 + (double)m1 * m1 + (double)m2 * m2;

        if (fd)  { sFext = fesq; sForce = fsq; }
        if (fr)  { sMom = msq; }
        if (pin) { sNeu = msq; }
    }

    unsigned long long cfd  = __popcll(__ballot(fd));
    unsigned long long cfr  = __popcll(__ballot(fr));
    unsigned long long cpin = __popcll(__ballot(pin));

    sFext  = waveSumD(sFext);
    sForce = waveSumD(sForce);
    sMom   = waveSumD(sMom);
    sNeu   = waveSumD(sNeu);

    if ((threadIdx.x & 63) == 0) {
        atomicAdd(&sc->S_Fext,  sFext);
        atomicAdd(&sc->S_force, sForce);
        atomicAdd(&sc->S_mom,   sMom);
        atomicAdd(&sc->S_neu,   sNeu);
        atomicAdd(&sc->n_fd,  cfd);
        atomicAdd(&sc->n_fr,  cfr);
        atomicAdd(&sc->n_pin, cpin);
    }
}

// ============ finalize ============

__global__ void finalize_kernel(const Scalars* __restrict__ sc, float* __restrict__ out)
{
    double n_fd = (double)(sc->n_fd > 0ull ? sc->n_fd : 1ull);
    double n_fr = (double)(sc->n_fr > 0ull ? sc->n_fr : 1ull);

    double F_char = sqrt(sc->S_Fext / (3.0 * n_fd));
    if (F_char < 1.0) F_char = 1.0;

    double q_max = (double)__int_as_float(sc->q_max_bits);
    if (q_max < 1.0) q_max = 1.0;
    double L_max = (double)__int_as_float(sc->L_max_bits);
    double M_char = q_max * L_max * sc->L_sum / 8.0;
    if (M_char < 1.0) M_char = 1.0;

    double L_force  = sc->S_force / (3.0 * n_fd) / (F_char * F_char);
    double L_moment = sc->S_mom   / (3.0 * n_fr) / (M_char * M_char);
    double L_neu = 0.0;
    if (sc->n_pin > 0ull) {
        L_neu = sc->S_neu / (3.0 * (double)sc->n_pin) / (M_char * M_char);
    }
    double L_kin = 0.5 * sc->S_kin / (double)N_ELEMS_C;

    out[0] = (float)(1.0 * L_force + 1.0 * L_moment + 1.0 * L_neu + 0.1 * L_kin);
}

// ============ host ============

extern "C" void kernel_launch(void* const* d_in, const int* in_sizes, int n_in,
                              void* d_out, int out_size, void* d_ws, size_t ws_size,
                              hipStream_t stream) {
    const float* phi       = (const float*)d_in[0];
    const float* grad_ux   = (const float*)d_in[1];
    const float* grad_uz   = (const float*)d_in[2];
    const float* grad_phi  = (const float*)d_in[3];
    const float* prop_E    = (const float*)d_in[4];
    const float* prop_A    = (const float*)d_in[5];
    const float* prop_I22  = (const float*)d_in[6];
    const float* elem_len  = (const float*)d_in[7];
    const float* elem_dir  = (const float*)d_in[8];
    const float* elem_load = (const float*)d_in[9];
    const float* bc_disp   = (const float*)d_in[10];
    const float* bc_rot    = (const float*)d_in[11];
    const int*   conn      = (const int*)d_in[12];

    const size_t szCounts  = (size_t)N_NODES_C * 4;
    const size_t szSc      = 128;
    const size_t szOffsets = (size_t)N_NODES_C * 4;
    const size_t szTiles   = 4096;
    const size_t szRank    = (size_t)N_ELEMS_C * 8;     // 32 MB
    const size_t szEid     = (size_t)N_ENDP_C * 4;      // 32 MB
    const size_t szRec     = (size_t)N_ELEMS_C * 48;    // 192 MB

    const size_t needB  = szCounts + szSc + szOffsets + szTiles + szEid;            // ~40.0 MB
    const size_t needB1 = needB + szRank;                                           // ~72.0 MB
    const size_t needA2 = needB + szRec;                                            // ~232.0 MB
    const size_t needA1 = needB + szRank + szRec;                                   // ~264.0 MB

    const int egrid = (N_ELEMS_C + 255) / 256;
    const int ngrid = (N_NODES_C + 255) / 256;

    if (ws_size >= needA1) {
        // Tier A1: rank build (8M atomics) + packed records + gather node pass
        char* p = (char*)d_ws;
        int* counts   = (int*)p;      p += szCounts;
        Scalars* sc   = (Scalars*)p;  p += szSc;
        int* offsets  = (int*)p;      p += szOffsets;
        int* tileSums = (int*)p;      p += szTiles;
        int2* rank2   = (int2*)p;     p += szRank;
        int* eidside  = (int*)p;      p += szEid;
        float4* rec   = (float4*)p;

        hipMemsetAsync(counts, 0, szCounts + szSc, stream);
        rank_build<<<egrid, 256, 0, stream>>>(conn, elem_len, elem_load, counts, rank2, sc);
        tile_sum<<<N_TILES, 256, 0, stream>>>(counts, tileSums);
        scan_tiles<<<1, 1024, 0, stream>>>(tileSums);
        scan_within<<<N_TILES, 256, 0, stream>>>(counts, tileSums, offsets);
        pack_fill<<<egrid, 256, 0, stream>>>(
            grad_ux, grad_uz, grad_phi, prop_E, prop_A, prop_I22,
            elem_len, elem_dir, elem_load, conn, offsets, counts, rank2, eidside, rec);
        node_pass_A<<<ngrid, 256, 0, stream>>>(
            phi, grad_ux, grad_uz, bc_disp, bc_rot, offsets, eidside, rec, sc);
        finalize_kernel<<<1, 1, 0, stream>>>(sc, (float*)d_out);
    } else if (ws_size >= needA2) {
        // Tier A2: cursor build (16M atomics) + packed records + gather node pass
        char* p = (char*)d_ws;
        int* counts   = (int*)p;      p += szCounts;
        Scalars* sc   = (Scalars*)p;  p += szSc;
        int* offsets  = (int*)p;      p += szOffsets;
        int* tileSums = (int*)p;      p += szTiles;
        int* eidside  = (int*)p;      p += szEid;
        float4* rec   = (float4*)p;

        hipMemsetAsync(counts, 0, szCounts + szSc, stream);
        hist_scalars<<<egrid, 256, 0, stream>>>(conn, elem_len, elem_load, counts, sc);
        tile_sum<<<N_TILES, 256, 0, stream>>>(counts, tileSums);
        scan_tiles<<<1, 1024, 0, stream>>>(tileSums);
        scan_within<<<N_TILES, 256, 0, stream>>>(counts, tileSums, offsets);
        pack_fill<<<egrid, 256, 0, stream>>>(
            grad_ux, grad_uz, grad_phi, prop_E, prop_A, prop_I22,
            elem_len, elem_dir, elem_load, conn, offsets, counts, (const int2*)nullptr,
            eidside, rec);
        node_pass_A<<<ngrid, 256, 0, stream>>>(
            phi, grad_ux, grad_uz, bc_disp, bc_rot, offsets, eidside, rec, sc);
        finalize_kernel<<<1, 1, 0, stream>>>(sc, (float*)d_out);
    } else if (ws_size >= needB1) {
        // Tier B1: rank build (8M atomics) + recompute node pass
        char* p = (char*)d_ws;
        int* counts   = (int*)p;      p += szCounts;
        Scalars* sc   = (Scalars*)p;  p += szSc;
        int* offsets  = (int*)p;      p += szOffsets;
        int* tileSums = (int*)p;      p += szTiles;
        int2* rank2   = (int2*)p;     p += szRank;
        int* eidside  = (int*)p;

        hipMemsetAsync(counts, 0, szCounts + szSc, stream);
        rank_build<<<egrid, 256, 0, stream>>>(conn, elem_len, elem_load, counts, rank2, sc);
        tile_sum<<<N_TILES, 256, 0, stream>>>(counts, tileSums);
        scan_tiles<<<1, 1024, 0, stream>>>(tileSums);
        scan_within<<<N_TILES, 256, 0, stream>>>(counts, tileSums, offsets);
        fill_rank<<<egrid, 256, 0, stream>>>(conn, rank2, offsets, eidside);
        node_reduce_csr<<<ngrid, 256, 0, stream>>>(
            phi, grad_ux, grad_uz, grad_phi,
            prop_E, prop_A, prop_I22, elem_len, elem_dir, elem_load, conn,
            bc_disp, bc_rot, offsets, eidside, sc);
        finalize_kernel<<<1, 1, 0, stream>>>(sc, (float*)d_out);
    } else if (ws_size >= needB) {
        // Tier B: R3 exact
        char* p = (char*)d_ws;
        int* counts   = (int*)p;      p += szCounts;
        Scalars* sc   = (Scalars*)p;  p += szSc;
        int* offsets  = (int*)p;      p += szOffsets;
        int* tileSums = (int*)p;      p += szTiles;
        int* eidside  = (int*)p;

        hipMemsetAsync(counts, 0, szCounts + szSc, stream);
        hist_scalars<<<egrid, 256, 0, stream>>>(conn, elem_len, elem_load, counts, sc);
        tile_sum<<<N_TILES, 256, 0, stream>>>(counts, tileSums);
        scan_tiles<<<1, 1024, 0, stream>>>(tileSums);
        scan_within<<<N_TILES, 256, 0, stream>>>(counts, tileSums, offsets);
        fill_csr<<<egrid, 256, 0, stream>>>(conn, offsets, counts, eidside);
        node_reduce_csr<<<ngrid, 256, 0, stream>>>(
            phi, grad_ux, grad_uz, grad_phi,
            prop_E, prop_A, prop_I22, elem_len, elem_dir, elem_load, conn,
            bc_disp, bc_rot, offsets, eidside, sc);
        finalize_kernel<<<1, 1, 0, stream>>>(sc, (float*)d_out);
    } else {
        // Tier C: R1 atomic fallback (36 MB)
        const size_t nodeArr = 3ull * N_NODES_C;
        float* F_int = (float*)d_ws;
        float* M_int = F_int + nodeArr;
        float* F_ext = M_int + nodeArr;
        Scalars* sc  = (Scalars*)(F_ext + nodeArr);

        hipMemsetAsync(d_ws, 0, nodeArr * 3ull * sizeof(float) + sizeof(Scalars), stream);
        elem_kernel_atomic<<<egrid, 256, 0, stream>>>(
            phi, grad_ux, grad_uz, grad_phi,
            prop_E, prop_A, prop_I22, elem_len, elem_dir, elem_load, conn,
            F_int, M_int, F_ext, sc);
        node_kernel_atomic<<<ngrid, 256, 0, stream>>>(
            bc_disp, bc_rot, F_int, M_int, F_ext, sc);
        finalize_kernel<<<1, 1, 0, stream>>>(sc, (float*)d_out);
    }
}